// Round 6
// baseline (298.703 us; speedup 1.0000x reference)
//
#include <hip/hip_runtime.h>

typedef unsigned short u16;
typedef __attribute__((ext_vector_type(4))) unsigned short u16x4;
typedef __attribute__((ext_vector_type(2))) unsigned u32x2;
typedef __attribute__((ext_vector_type(8))) __bf16 bf16x8;
typedef __attribute__((ext_vector_type(2))) __bf16 bf16x2;
typedef __attribute__((ext_vector_type(4))) float f32x4;

#define DEV __device__ __forceinline__

DEV u16 f2b(float f) {
    union { float f; unsigned u; } v; v.f = f;
    unsigned r = v.u + 0x7FFFu + ((v.u >> 16) & 1u);
    return (u16)(r >> 16);
}
DEV unsigned pk2(float a, float b) {   // two f32 -> packed bf16x2 (RNE, hw cvt)
    bf16x2 t; t.x = (__bf16)a; t.y = (__bf16)b;
    union { bf16x2 v; unsigned u; } c; c.v = t; return c.u;
}

// async global->LDS, 16B per lane; lds dest = wave-uniform base + lane*16
DEV void gl_lds16(const u16* g, const u16* l) {
    __builtin_amdgcn_global_load_lds(
        (__attribute__((address_space(1))) void*)(unsigned long long)g,
        (__attribute__((address_space(3))) void*)(unsigned long long)l,
        16, 0, 0);
}

// fused prep: blocks [0,8192) convert x fp32->bf16; [8192,9216) transpose W0..3
__global__ __launch_bounds__(256) void k_prep(const float* __restrict__ xf, u16* __restrict__ xb,
                                              const float* w0, const float* w1,
                                              const float* w2, const float* w3,
                                              u16* __restrict__ dst)
{
    __shared__ u16 t[64][68];
    int bx = blockIdx.x;
    if (bx < 8192) {
        size_t base = (size_t)bx * 1024 + threadIdx.x * 4;
        float4 v = *(const float4*)&xf[base];
        u16x4 o; o.x = f2b(v.x); o.y = f2b(v.y); o.z = f2b(v.z); o.w = f2b(v.w);
        *(u16x4*)&xb[base] = o;
        return;
    }
    bx -= 8192;
    int z = bx >> 8, tile = bx & 255;
    const float* src = z == 0 ? w0 : z == 1 ? w1 : z == 2 ? w2 : w3;
    u16* d = dst + (size_t)z * 1048576;
    int tx = threadIdx.x & 15, ty = threadIdx.x >> 4;
    int c0 = (tile & 15) * 64, r0 = (tile >> 4) * 64;
#pragma unroll
    for (int i = 0; i < 4; i++) {
        int r = ty + i * 16;
        float4 v = *(const float4*)&src[(size_t)(r0 + r) * 1024 + c0 + tx * 4];
        t[r][tx * 4 + 0] = f2b(v.x); t[r][tx * 4 + 1] = f2b(v.y);
        t[r][tx * 4 + 2] = f2b(v.z); t[r][tx * 4 + 3] = f2b(v.w);
    }
    __syncthreads();
#pragma unroll
    for (int i = 0; i < 4; i++) {
        int cl = ty + i * 16;
        u16x4 v;
        v.x = t[tx * 4 + 0][cl];
        v.y = t[tx * 4 + 1][cl];
        v.z = t[tx * 4 + 2][cl];
        v.w = t[tx * 4 + 3][cl];
        *(u16x4*)&d[(size_t)(c0 + cl) * 1024 + r0 + tx * 4] = v;
    }
}

// ---------------------------------------------------------------------------
// 128x128-tile bf16 GEMM v4: dbuf LDS (1 barrier/K-step), pair-row XOR swizzle,
// operand-swapped epilogue for wide stores.
// MODE 0: bf16 row-major (swapped, u16x4 stores), with oscale
// MODE 1: Vt[b*16+h][d][n] scatter (unswapped; reg dim = token)
// MODE 2: fp32 row-major (swapped, float4 stores)
// ---------------------------------------------------------------------------
template <int MODE>
DEV void gemm128(const u16* __restrict__ A, const u16* __restrict__ BT,
                 const float* __restrict__ bias,
                 u16* __restrict__ Cb, float* __restrict__ Cf,
                 int N, int K, int m0, int n0, float oscale,
                 u16* As, u16* Bs)
{
    const int tid = threadIdx.x;
    const int w = tid >> 6, lane = tid & 63, quad = lane >> 4, l16 = lane & 15;
    const int wr = w >> 1, wc = w & 1;
    f32x4 acc[4][4] = {};
    const int NS = K >> 5;

    int soff[2], ldst[2];
#pragma unroll
    for (int i = 0; i < 2; i++) {
        int L = (w * 2 + i) * 512 + lane * 8;
        int pr = L >> 6, cp = (L >> 3) & 7;
        int c = cp ^ (pr & 7);
        int r = pr * 2 + (c >> 2);
        soff[i] = r * K + (c & 3) * 8;
        ldst[i] = (w * 2 + i) * 512;
    }
    const u16* Ap = A + (size_t)m0 * K;
    const u16* Bp = BT + (size_t)n0 * K;

    int aoff[4], boff[4];
#pragma unroll
    for (int mi = 0; mi < 4; mi++) {
        int row = wr * 64 + mi * 16 + l16;
        aoff[mi] = (row >> 1) * 64 + (((((row & 1) << 2) | quad) ^ ((row >> 1) & 7)) << 3);
        int rowb = wc * 64 + mi * 16 + l16;
        boff[mi] = (rowb >> 1) * 64 + (((((rowb & 1) << 2) | quad) ^ ((rowb >> 1) & 7)) << 3);
    }

#pragma unroll
    for (int i = 0; i < 2; i++) {
        gl_lds16(Ap + soff[i], As + ldst[i]);
        gl_lds16(Bp + soff[i], Bs + ldst[i]);
    }
    __syncthreads();

    for (int s = 0; s < NS; s++) {
        const u16* curA = As + (s & 1) * 4096;
        const u16* curB = Bs + (s & 1) * 4096;
        if (s + 1 < NS) {
            int kk = (s + 1) * 32;
            u16* nA = As + ((s + 1) & 1) * 4096;
            u16* nB = Bs + ((s + 1) & 1) * 4096;
#pragma unroll
            for (int i = 0; i < 2; i++) {
                gl_lds16(Ap + soff[i] + kk, nA + ldst[i]);
                gl_lds16(Bp + soff[i] + kk, nB + ldst[i]);
            }
        }
        bf16x8 a[4], b[4];
#pragma unroll
        for (int mi = 0; mi < 4; mi++) a[mi] = *(const bf16x8*)&curA[aoff[mi]];
#pragma unroll
        for (int ni = 0; ni < 4; ni++) b[ni] = *(const bf16x8*)&curB[boff[ni]];
        if (MODE == 1) {
#pragma unroll
            for (int mi = 0; mi < 4; mi++)
#pragma unroll
                for (int ni = 0; ni < 4; ni++)
                    acc[mi][ni] = __builtin_amdgcn_mfma_f32_16x16x32_bf16(a[mi], b[ni], acc[mi][ni], 0, 0, 0);
        } else {
            // swapped: acc[ni][mi]; D col(l16)=token, D row(quad*4+reg)=out-col
#pragma unroll
            for (int ni = 0; ni < 4; ni++)
#pragma unroll
                for (int mi = 0; mi < 4; mi++)
                    acc[ni][mi] = __builtin_amdgcn_mfma_f32_16x16x32_bf16(b[ni], a[mi], acc[ni][mi], 0, 0, 0);
        }
        __syncthreads();
    }

    if (MODE == 1) {
        float bs[4];
#pragma unroll
        for (int ni = 0; ni < 4; ni++)
            bs[ni] = bias[n0 + wc * 64 + ni * 16 + l16];
        int bb = m0 >> 10;
        int nbase = (m0 & 1023) + wr * 64;
#pragma unroll
        for (int mi = 0; mi < 4; mi++) {
            int nrow = nbase + mi * 16 + quad * 4;
#pragma unroll
            for (int ni = 0; ni < 4; ni++) {
                int col = n0 + wc * 64 + ni * 16 + l16;
                int hh = col >> 6, dd = col & 63;
                u16x4 pk;
                pk.x = f2b(acc[mi][ni][0] + bs[ni]);
                pk.y = f2b(acc[mi][ni][1] + bs[ni]);
                pk.z = f2b(acc[mi][ni][2] + bs[ni]);
                pk.w = f2b(acc[mi][ni][3] + bs[ni]);
                *(u16x4*)&Cb[(size_t)(bb * 16 + hh) * 65536 + (size_t)dd * 1024 + nrow] = pk;
            }
        }
    } else {
#pragma unroll
        for (int ni = 0; ni < 4; ni++) {
            int cb = n0 + wc * 64 + ni * 16 + quad * 4;
            float4 bv = *(const float4*)&bias[cb];
#pragma unroll
            for (int mi = 0; mi < 4; mi++) {
                int t = m0 + wr * 64 + mi * 16 + l16;
                if (MODE == 0) {
                    u16x4 pk;
                    pk.x = f2b((acc[ni][mi][0] + bv.x) * oscale);
                    pk.y = f2b((acc[ni][mi][1] + bv.y) * oscale);
                    pk.z = f2b((acc[ni][mi][2] + bv.z) * oscale);
                    pk.w = f2b((acc[ni][mi][3] + bv.w) * oscale);
                    *(u16x4*)&Cb[(size_t)t * N + cb] = pk;
                } else {
                    float4 o;
                    o.x = acc[ni][mi][0] + bv.x; o.y = acc[ni][mi][1] + bv.y;
                    o.z = acc[ni][mi][2] + bv.z; o.w = acc[ni][mi][3] + bv.w;
                    *(float4*)&Cf[(size_t)t * N + cb] = o;
                }
            }
        }
    }
}

// fused Q/K/V projection: grid (24, 64); Q pre-scaled by log2(e)/8
__global__ __launch_bounds__(256, 5) void k_qkv(const u16* __restrict__ x, const u16* __restrict__ WT,
                                                const float* __restrict__ bq, const float* __restrict__ bk,
                                                const float* __restrict__ bv,
                                                u16* __restrict__ QK, u16* __restrict__ Vt)
{
    __shared__ u16 As[8192], Bs[8192];
    int sel = blockIdx.x >> 3;
    int m0 = blockIdx.y * 128, n0 = (blockIdx.x & 7) * 128;
    if (sel == 2) {
        gemm128<1>(x, WT + (size_t)2 * 1048576, bv, Vt, (float*)0, 1024, 1024, m0, n0, 1.0f, As, Bs);
    } else {
        const float* bias = sel == 0 ? bq : bk;
        float sc = sel == 0 ? 0.18033688011f : 1.0f;  // log2(e)/8
        gemm128<0>(x, WT + (size_t)sel * 1048576, bias, QK + (size_t)sel * 8388608, (float*)0,
                   1024, 1024, m0, n0, sc, As, Bs);
    }
}

// output projection (fp32 out): grid (8, 64)
__global__ __launch_bounds__(256, 5) void k_out(const u16* __restrict__ A, const u16* __restrict__ WoT,
                                                const float* __restrict__ bo, float* __restrict__ C)
{
    __shared__ u16 As[8192], Bs[8192];
    gemm128<2>(A, WoT, bo, (u16*)0, C, 1024, 1024, blockIdx.y * 128, blockIdx.x * 128, 1.0f, As, Bs);
}

// ---------------------------------------------------------------------------
// attention v3: wave-private q rows, K/V dbuf, 1 barrier/kt, swizzled staging.
// Row-sum l(q) via ones-MFMA (no VALU reduction, no shfl); PV operand-swapped
// so q lands on the lane dim -> l pre-aligned, O stores 8B-packed.
// grid (8, 128)
// ---------------------------------------------------------------------------
__global__ __launch_bounds__(256, 3) void k_attn(const u16* __restrict__ Q, const u16* __restrict__ K,
                                                 const u16* __restrict__ Vt, u16* __restrict__ O)
{
    __shared__ u16 lds[25600];   // 16384 (KV dbuf) + 9216 (Ps: 4 waves x 32 x 72)
    const int tid = threadIdx.x, w = tid >> 6, lane = tid & 63, quad = lane >> 4, l16 = lane & 15;
    const int bh = blockIdx.y, b = bh >> 4, h = bh & 15;
    const int q0 = blockIdx.x * 128;
    const u16* Qp = Q + ((size_t)b * 1024 + q0) * 1024 + h * 64;
    const u16* Kp = K + (size_t)b * 1048576 + h * 64;
    const u16* Vp = Vt + (size_t)bh * 65536;
    u16* Op = O + ((size_t)b * 1024 + q0) * 1024 + h * 64;
    u16* Pw = lds + 16384 + w * 2304;   // 32 rows x 72 u16, wave-private

#pragma unroll
    for (int i = 0; i < 4; i++) {
        int p = (w * 4 + i) * 64 + lane;
        int row = p >> 3, c = (p & 7) ^ (row & 7);
        gl_lds16(Qp + (size_t)row * 1024 + c * 8, lds + (w * 4 + i) * 512);
    }
    __syncthreads();
    bf16x8 qa[2][2];
#pragma unroll
    for (int ni = 0; ni < 2; ni++)
#pragma unroll
        for (int d2 = 0; d2 < 2; d2++)
            qa[ni][d2] = *(const bf16x8*)&lds[(w * 32 + ni * 16 + l16) * 64 + ((d2 * 4 + quad) ^ (l16 & 7)) * 8];
#pragma unroll
    for (int i = 0; i < 2; i++) {
        int p = (w * 2 + i) * 64 + lane;
        int row = p >> 3, c = (p & 7) ^ (row & 7);
        gl_lds16(Kp + (size_t)row * 1024 + c * 8, lds + 8192 + (w * 2 + i) * 512);
        gl_lds16(Vp + (size_t)row * 1024 + c * 8, lds + 8192 + 4096 + (w * 2 + i) * 512);
    }
    __syncthreads();

    bf16x8 ones;
#pragma unroll
    for (int j = 0; j < 8; j++) ones[j] = (__bf16)1.0f;

    f32x4 acc_o[4][2] = {};   // [di][ni]: D[d][q], col=q, row=d
    f32x4 acc_l[2] = {};      // [ni]: l(q) in every reg

    for (int kt = 0; kt < 16; kt++) {
        const u16* buf = lds + (((kt & 1) ^ 1) << 13);
        if (kt < 15) {
            int k0n = (kt + 1) * 64;
            u16* dst = lds + ((kt & 1) << 13);
#pragma unroll
            for (int i = 0; i < 2; i++) {
                int p = (w * 2 + i) * 64 + lane;
                int row = p >> 3, c = (p & 7) ^ (row & 7);
                gl_lds16(Kp + (size_t)(k0n + row) * 1024 + c * 8, dst + (w * 2 + i) * 512);
                gl_lds16(Vp + (size_t)row * 1024 + k0n + c * 8, dst + 4096 + (w * 2 + i) * 512);
            }
        }

        // S^T: D[k=mi*16+quad*4+reg][q=w*32+ni*16+l16]
        f32x4 s[4][2] = {};
#pragma unroll
        for (int d2 = 0; d2 < 2; d2++) {
            bf16x8 ka[4];
#pragma unroll
            for (int mi = 0; mi < 4; mi++)
                ka[mi] = *(const bf16x8*)&buf[(mi * 16 + l16) * 64 + ((d2 * 4 + quad) ^ (l16 & 7)) * 8];
#pragma unroll
            for (int mi = 0; mi < 4; mi++)
#pragma unroll
                for (int ni = 0; ni < 2; ni++)
                    s[mi][ni] = __builtin_amdgcn_mfma_f32_16x16x32_bf16(ka[mi], qa[ni][d2], s[mi][ni], 0, 0, 0);
        }

        // exp2 (Q pre-scaled), pack 4 consecutive k -> wave-private Ps
#pragma unroll
        for (int ni = 0; ni < 2; ni++)
#pragma unroll
            for (int mi = 0; mi < 4; mi++) {
                float e0 = __builtin_amdgcn_exp2f(s[mi][ni][0]);
                float e1 = __builtin_amdgcn_exp2f(s[mi][ni][1]);
                float e2 = __builtin_amdgcn_exp2f(s[mi][ni][2]);
                float e3 = __builtin_amdgcn_exp2f(s[mi][ni][3]);
                u32x2 pk; pk.x = pk2(e0, e1); pk.y = pk2(e2, e3);
                *(u32x2*)&Pw[(ni * 16 + l16) * 72 + mi * 16 + quad * 4] = pk;
            }

        // O^T[d][q] += V^T[d][k] P^T[k][q]; l(q) += ones*P; same-wave LDS RAW
#pragma unroll
        for (int ks = 0; ks < 2; ks++) {
            bf16x8 pa[2], vb[4];
#pragma unroll
            for (int ni = 0; ni < 2; ni++)
                pa[ni] = *(const bf16x8*)&Pw[(ni * 16 + l16) * 72 + ks * 32 + quad * 8];
#pragma unroll
            for (int di = 0; di < 4; di++)
                vb[di] = *(const bf16x8*)&buf[4096 + (di * 16 + l16) * 64 + ((ks * 4 + quad) ^ (l16 & 7)) * 8];
#pragma unroll
            for (int ni = 0; ni < 2; ni++) {
                acc_l[ni] = __builtin_amdgcn_mfma_f32_16x16x32_bf16(ones, pa[ni], acc_l[ni], 0, 0, 0);
#pragma unroll
                for (int di = 0; di < 4; di++)
                    acc_o[di][ni] = __builtin_amdgcn_mfma_f32_16x16x32_bf16(vb[di], pa[ni], acc_o[di][ni], 0, 0, 0);
            }
        }
        __syncthreads();
    }

    // normalize + store: q = w*32 + ni*16 + l16 (lane dim), d = di*16+quad*4+reg
#pragma unroll
    for (int ni = 0; ni < 2; ni++) {
        float inv = __builtin_amdgcn_rcpf(acc_l[ni][0]);
        int q = w * 32 + ni * 16 + l16;
#pragma unroll
        for (int di = 0; di < 4; di++) {
            u32x2 po;
            po.x = pk2(acc_o[di][ni][0] * inv, acc_o[di][ni][1] * inv);
            po.y = pk2(acc_o[di][ni][2] * inv, acc_o[di][ni][3] * inv);
            *(u32x2*)&Op[(size_t)q * 1024 + di * 16 + quad * 4] = po;
        }
    }
}

extern "C" void kernel_launch(void* const* d_in, const int* in_sizes, int n_in,
                              void* d_out, int out_size, void* d_ws, size_t ws_size,
                              hipStream_t stream)
{
    (void)in_sizes; (void)n_in; (void)out_size; (void)ws_size;
    // inputs (fp32): 0:x 4:Wq 5:bq 6:Wk 7:bk 8:Wv 9:bv 10:Wo 11:bo
    // 1,2,3,12..19: conditioning — mathematically cancels in softmax.
    const float* xf  = (const float*)d_in[0];
    const float* Wqf = (const float*)d_in[4];  const float* bqf = (const float*)d_in[5];
    const float* Wkf = (const float*)d_in[6];  const float* bkf = (const float*)d_in[7];
    const float* Wvf = (const float*)d_in[8];  const float* bvf = (const float*)d_in[9];
    const float* Wof = (const float*)d_in[10]; const float* bof = (const float*)d_in[11];

    u16* ws  = (u16*)d_ws;
    u16* Qw  = ws;                              // 8M el bf16 (pre-scaled by log2e/8)
    u16* Kw  = ws + (size_t)8388608;            // 8M el bf16
    u16* Vtw = ws + (size_t)16777216;           // 8M el bf16 [b*16+h][64][1024]
    u16* WT  = ws + (size_t)25165824;           // 4M el bf16 [4][n=1024][k=1024]
    u16* xb  = ws + (size_t)29360128;           // 8M el bf16 x; reused as AO after k_qkv
    u16* AO  = xb;

    k_prep<<<9216, 256, 0, stream>>>(xf, xb, Wqf, Wkf, Wvf, Wof, WT);
    k_qkv<<<dim3(24, 64), 256, 0, stream>>>(xb, WT, bqf, bkf, bvf, Qw, Vtw);
    k_attn<<<dim3(8, 128), 256, 0, stream>>>(Qw, Kw, Vtw, AO);
    k_out<<<dim3(8, 64), 256, 0, stream>>>(AO, WT + (size_t)3145728, bof, (float*)d_out);
}

// Round 7
// 270.321 us; speedup vs baseline: 1.1050x; 1.1050x over previous
//
#include <hip/hip_runtime.h>

typedef unsigned short u16;
typedef __attribute__((ext_vector_type(4))) unsigned short u16x4;
typedef __attribute__((ext_vector_type(2))) unsigned u32x2;
typedef __attribute__((ext_vector_type(8))) __bf16 bf16x8;
typedef __attribute__((ext_vector_type(2))) __bf16 bf16x2;
typedef __attribute__((ext_vector_type(4))) float f32x4;

#define DEV __device__ __forceinline__

DEV u16 f2b(float f) {
    union { float f; unsigned u; } v; v.f = f;
    unsigned r = v.u + 0x7FFFu + ((v.u >> 16) & 1u);
    return (u16)(r >> 16);
}
DEV unsigned pk2(float a, float b) {   // two f32 -> packed bf16x2 (RNE, hw cvt)
    bf16x2 t; t.x = (__bf16)a; t.y = (__bf16)b;
    union { bf16x2 v; unsigned u; } c; c.v = t; return c.u;
}
DEV u16 cvt1(float f) {
    __bf16 h = (__bf16)f;
    union { __bf16 h; u16 u; } c; c.h = h; return c.u;
}

// async global->LDS, 16B per lane; lds dest = wave-uniform base + lane*16
DEV void gl_lds16(const u16* g, const u16* l) {
    __builtin_amdgcn_global_load_lds(
        (__attribute__((address_space(1))) void*)(unsigned long long)g,
        (__attribute__((address_space(3))) void*)(unsigned long long)l,
        16, 0, 0);
}

// fused prep: blocks [0,8192) convert x fp32->bf16; [8192,9216) transpose W0..3
__global__ __launch_bounds__(256) void k_prep(const float* __restrict__ xf, u16* __restrict__ xb,
                                              const float* w0, const float* w1,
                                              const float* w2, const float* w3,
                                              u16* __restrict__ dst)
{
    __shared__ u16 t[64][68];
    int bx = blockIdx.x;
    if (bx < 8192) {
        size_t base = (size_t)bx * 1024 + threadIdx.x * 4;
        float4 v = *(const float4*)&xf[base];
        u16x4 o; o.x = f2b(v.x); o.y = f2b(v.y); o.z = f2b(v.z); o.w = f2b(v.w);
        *(u16x4*)&xb[base] = o;
        return;
    }
    bx -= 8192;
    int z = bx >> 8, tile = bx & 255;
    const float* src = z == 0 ? w0 : z == 1 ? w1 : z == 2 ? w2 : w3;
    u16* d = dst + (size_t)z * 1048576;
    int tx = threadIdx.x & 15, ty = threadIdx.x >> 4;
    int c0 = (tile & 15) * 64, r0 = (tile >> 4) * 64;
#pragma unroll
    for (int i = 0; i < 4; i++) {
        int r = ty + i * 16;
        float4 v = *(const float4*)&src[(size_t)(r0 + r) * 1024 + c0 + tx * 4];
        t[r][tx * 4 + 0] = f2b(v.x); t[r][tx * 4 + 1] = f2b(v.y);
        t[r][tx * 4 + 2] = f2b(v.z); t[r][tx * 4 + 3] = f2b(v.w);
    }
    __syncthreads();
#pragma unroll
    for (int i = 0; i < 4; i++) {
        int cl = ty + i * 16;
        u16x4 v;
        v.x = t[tx * 4 + 0][cl];
        v.y = t[tx * 4 + 1][cl];
        v.z = t[tx * 4 + 2][cl];
        v.w = t[tx * 4 + 3][cl];
        *(u16x4*)&d[(size_t)(c0 + cl) * 1024 + r0 + tx * 4] = v;
    }
}

// ---------------------------------------------------------------------------
// 128x128-tile bf16 GEMM v3 (round-5 proven): dbuf LDS (1 barrier/K-step),
// pair-row XOR swizzle (0 bank conflicts), row-dense coalesced epilogue.
// mode 0: bf16 row-major; mode 1: Vt[b*16+h][d][n] scatter; mode 2: fp32.
// NOTE: do NOT operand-swap the epilogue — putting the token on the lane dim
// scatters 8B/lane across rows and ~doubles HBM WRITE_SIZE (round-6 regression).
// ---------------------------------------------------------------------------
DEV void gemm128(const u16* __restrict__ A, const u16* __restrict__ BT,
                 const float* __restrict__ bias,
                 u16* __restrict__ Cb, float* __restrict__ Cf,
                 int N, int K, int m0, int n0, int mode, float oscale,
                 u16* As, u16* Bs)
{
    const int tid = threadIdx.x;
    const int w = tid >> 6, lane = tid & 63, quad = lane >> 4, l16 = lane & 15;
    const int wr = w >> 1, wc = w & 1;
    f32x4 acc[4][4] = {};
    const int NS = K >> 5;

    int soff[2], ldst[2];
#pragma unroll
    for (int i = 0; i < 2; i++) {
        int L = (w * 2 + i) * 512 + lane * 8;
        int pr = L >> 6, cp = (L >> 3) & 7;
        int c = cp ^ (pr & 7);
        int r = pr * 2 + (c >> 2);
        soff[i] = r * K + (c & 3) * 8;
        ldst[i] = (w * 2 + i) * 512;
    }
    const u16* Ap = A + (size_t)m0 * K;
    const u16* Bp = BT + (size_t)n0 * K;

    int aoff[4], boff[4];
#pragma unroll
    for (int mi = 0; mi < 4; mi++) {
        int row = wr * 64 + mi * 16 + l16;
        aoff[mi] = (row >> 1) * 64 + (((((row & 1) << 2) | quad) ^ ((row >> 1) & 7)) << 3);
        int rowb = wc * 64 + mi * 16 + l16;
        boff[mi] = (rowb >> 1) * 64 + (((((rowb & 1) << 2) | quad) ^ ((rowb >> 1) & 7)) << 3);
    }

#pragma unroll
    for (int i = 0; i < 2; i++) {
        gl_lds16(Ap + soff[i], As + ldst[i]);
        gl_lds16(Bp + soff[i], Bs + ldst[i]);
    }
    __syncthreads();

    for (int s = 0; s < NS; s++) {
        const u16* curA = As + (s & 1) * 4096;
        const u16* curB = Bs + (s & 1) * 4096;
        if (s + 1 < NS) {
            int kk = (s + 1) * 32;
            u16* nA = As + ((s + 1) & 1) * 4096;
            u16* nB = Bs + ((s + 1) & 1) * 4096;
#pragma unroll
            for (int i = 0; i < 2; i++) {
                gl_lds16(Ap + soff[i] + kk, nA + ldst[i]);
                gl_lds16(Bp + soff[i] + kk, nB + ldst[i]);
            }
        }
        bf16x8 a[4], b[4];
#pragma unroll
        for (int mi = 0; mi < 4; mi++) a[mi] = *(const bf16x8*)&curA[aoff[mi]];
#pragma unroll
        for (int ni = 0; ni < 4; ni++) b[ni] = *(const bf16x8*)&curB[boff[ni]];
#pragma unroll
        for (int mi = 0; mi < 4; mi++)
#pragma unroll
            for (int ni = 0; ni < 4; ni++)
                acc[mi][ni] = __builtin_amdgcn_mfma_f32_16x16x32_bf16(a[mi], b[ni], acc[mi][ni], 0, 0, 0);
        __syncthreads();
    }

    float bs[4];
#pragma unroll
    for (int ni = 0; ni < 4; ni++)
        bs[ni] = bias[n0 + wc * 64 + ni * 16 + l16];

    if (mode == 0) {
#pragma unroll
        for (int mi = 0; mi < 4; mi++) {
            int row = m0 + wr * 64 + mi * 16 + quad * 4;
#pragma unroll
            for (int ni = 0; ni < 4; ni++) {
                int col = n0 + wc * 64 + ni * 16 + l16;
#pragma unroll
                for (int r2 = 0; r2 < 4; r2++)
                    Cb[(size_t)(row + r2) * N + col] = f2b((acc[mi][ni][r2] + bs[ni]) * oscale);
            }
        }
    } else if (mode == 1) {
        int bb = m0 >> 10;
        int nbase = (m0 & 1023) + wr * 64;
#pragma unroll
        for (int mi = 0; mi < 4; mi++) {
            int nrow = nbase + mi * 16 + quad * 4;
#pragma unroll
            for (int ni = 0; ni < 4; ni++) {
                int col = n0 + wc * 64 + ni * 16 + l16;
                int hh = col >> 6, dd = col & 63;
                u16x4 pk;
                pk.x = f2b(acc[mi][ni][0] + bs[ni]);
                pk.y = f2b(acc[mi][ni][1] + bs[ni]);
                pk.z = f2b(acc[mi][ni][2] + bs[ni]);
                pk.w = f2b(acc[mi][ni][3] + bs[ni]);
                *(u16x4*)&Cb[(size_t)(bb * 16 + hh) * 65536 + (size_t)dd * 1024 + nrow] = pk;
            }
        }
    } else {
#pragma unroll
        for (int mi = 0; mi < 4; mi++) {
            int row = m0 + wr * 64 + mi * 16 + quad * 4;
#pragma unroll
            for (int ni = 0; ni < 4; ni++) {
                int col = n0 + wc * 64 + ni * 16 + l16;
#pragma unroll
                for (int r2 = 0; r2 < 4; r2++)
                    Cf[(size_t)(row + r2) * N + col] = acc[mi][ni][r2] + bs[ni];
            }
        }
    }
}

// fused Q/K/V projection: grid (24, 64); Q pre-scaled by log2(e)/8
__global__ __launch_bounds__(256, 4) void k_qkv(const u16* __restrict__ x, const u16* __restrict__ WT,
                                                const float* __restrict__ bq, const float* __restrict__ bk,
                                                const float* __restrict__ bv,
                                                u16* __restrict__ QK, u16* __restrict__ Vt)
{
    __shared__ u16 As[8192], Bs[8192];
    int sel = blockIdx.x >> 3;
    const float* bias = sel == 0 ? bq : (sel == 1 ? bk : bv);
    u16* C = sel == 2 ? Vt : QK + (size_t)sel * 8388608;
    float sc = sel == 0 ? 0.18033688011f : 1.0f;  // log2(e)/8
    gemm128(x, WT + (size_t)sel * 1048576, bias, C, (float*)0,
            1024, 1024, blockIdx.y * 128, (blockIdx.x & 7) * 128, sel == 2 ? 1 : 0, sc, As, Bs);
}

// output projection (fp32 out): grid (8, 64)
__global__ __launch_bounds__(256, 4) void k_out(const u16* __restrict__ A, const u16* __restrict__ WoT,
                                                const float* __restrict__ bo, float* __restrict__ C)
{
    __shared__ u16 As[8192], Bs[8192];
    gemm128(A, WoT, bo, (u16*)0, C, 1024, 1024, blockIdx.y * 128, blockIdx.x * 128, 2, 1.0f, As, Bs);
}

// ---------------------------------------------------------------------------
// attention v4: round-5 v2 structure (wave-private q rows, K/V dbuf, 1
// barrier/kt, swizzled staging, coalesced O store) + ones-MFMA row-sum:
// acc_l = mfma(P, ones) accumulates l(q) row-aligned with acc_o -> no VALU
// reduction, no shuffles, no Lp LDS. grid (8, 128)
// ---------------------------------------------------------------------------
__global__ __launch_bounds__(256, 3) void k_attn(const u16* __restrict__ Q, const u16* __restrict__ K,
                                                 const u16* __restrict__ Vt, u16* __restrict__ O)
{
    __shared__ u16 lds[25600];   // 16384 (KV dbuf) + 9216 (Ps: 4 waves x 32 x 72)
    const int tid = threadIdx.x, w = tid >> 6, lane = tid & 63, quad = lane >> 4, l16 = lane & 15;
    const int bh = blockIdx.y, b = bh >> 4, h = bh & 15;
    const int q0 = blockIdx.x * 128;
    const u16* Qp = Q + ((size_t)b * 1024 + q0) * 1024 + h * 64;
    const u16* Kp = K + (size_t)b * 1048576 + h * 64;
    const u16* Vp = Vt + (size_t)bh * 65536;
    u16* Op = O + ((size_t)b * 1024 + q0) * 1024 + h * 64;
    u16* Pw = lds + 16384 + w * 2304;   // 32 rows x 72 u16, wave-private

#pragma unroll
    for (int i = 0; i < 4; i++) {
        int p = (w * 4 + i) * 64 + lane;
        int row = p >> 3, c = (p & 7) ^ (row & 7);
        gl_lds16(Qp + (size_t)row * 1024 + c * 8, lds + (w * 4 + i) * 512);
    }
    __syncthreads();
    bf16x8 qa[2][2];
#pragma unroll
    for (int ni = 0; ni < 2; ni++)
#pragma unroll
        for (int d2 = 0; d2 < 2; d2++)
            qa[ni][d2] = *(const bf16x8*)&lds[(w * 32 + ni * 16 + l16) * 64 + ((d2 * 4 + quad) ^ (l16 & 7)) * 8];
#pragma unroll
    for (int i = 0; i < 2; i++) {
        int p = (w * 2 + i) * 64 + lane;
        int row = p >> 3, c = (p & 7) ^ (row & 7);
        gl_lds16(Kp + (size_t)row * 1024 + c * 8, lds + 8192 + (w * 2 + i) * 512);
        gl_lds16(Vp + (size_t)row * 1024 + c * 8, lds + 8192 + 4096 + (w * 2 + i) * 512);
    }
    __syncthreads();

    bf16x8 ones;
#pragma unroll
    for (int j = 0; j < 8; j++) ones[j] = (__bf16)1.0f;

    f32x4 acc_o[2][4] = {};   // [ni][di]: D[q][d], col=d(l16), row=q-part
    f32x4 acc_l[2] = {};      // [ni]: l(q), row-aligned with acc_o

    for (int kt = 0; kt < 16; kt++) {
        const u16* buf = lds + (((kt & 1) ^ 1) << 13);
        if (kt < 15) {
            int k0n = (kt + 1) * 64;
            u16* dst = lds + ((kt & 1) << 13);
#pragma unroll
            for (int i = 0; i < 2; i++) {
                int p = (w * 2 + i) * 64 + lane;
                int row = p >> 3, c = (p & 7) ^ (row & 7);
                gl_lds16(Kp + (size_t)(k0n + row) * 1024 + c * 8, dst + (w * 2 + i) * 512);
                gl_lds16(Vp + (size_t)row * 1024 + k0n + c * 8, dst + 4096 + (w * 2 + i) * 512);
            }
        }

        // S^T: D[k=mi*16+quad*4+reg][q=w*32+ni*16+l16]
        f32x4 s[4][2] = {};
#pragma unroll
        for (int d2 = 0; d2 < 2; d2++) {
            bf16x8 ka[4];
#pragma unroll
            for (int mi = 0; mi < 4; mi++)
                ka[mi] = *(const bf16x8*)&buf[(mi * 16 + l16) * 64 + ((d2 * 4 + quad) ^ (l16 & 7)) * 8];
#pragma unroll
            for (int mi = 0; mi < 4; mi++)
#pragma unroll
                for (int ni = 0; ni < 2; ni++)
                    s[mi][ni] = __builtin_amdgcn_mfma_f32_16x16x32_bf16(ka[mi], qa[ni][d2], s[mi][ni], 0, 0, 0);
        }

        // exp2 (Q pre-scaled), pack 4 consecutive k -> wave-private Ps
#pragma unroll
        for (int ni = 0; ni < 2; ni++)
#pragma unroll
            for (int mi = 0; mi < 4; mi++) {
                float e0 = __builtin_amdgcn_exp2f(s[mi][ni][0]);
                float e1 = __builtin_amdgcn_exp2f(s[mi][ni][1]);
                float e2 = __builtin_amdgcn_exp2f(s[mi][ni][2]);
                float e3 = __builtin_amdgcn_exp2f(s[mi][ni][3]);
                u32x2 pk; pk.x = pk2(e0, e1); pk.y = pk2(e2, e3);
                *(u32x2*)&Pw[(ni * 16 + l16) * 72 + mi * 16 + quad * 4] = pk;
            }

        // O[q][d] += P[q][k] V[k][d]; l(q) += P*ones; same-wave LDS RAW
#pragma unroll
        for (int ks = 0; ks < 2; ks++) {
            bf16x8 pa[2], vb[4];
#pragma unroll
            for (int ni = 0; ni < 2; ni++)
                pa[ni] = *(const bf16x8*)&Pw[(ni * 16 + l16) * 72 + ks * 32 + quad * 8];
#pragma unroll
            for (int di = 0; di < 4; di++)
                vb[di] = *(const bf16x8*)&buf[4096 + (di * 16 + l16) * 64 + ((ks * 4 + quad) ^ (l16 & 7)) * 8];
#pragma unroll
            for (int ni = 0; ni < 2; ni++) {
                acc_l[ni] = __builtin_amdgcn_mfma_f32_16x16x32_bf16(pa[ni], ones, acc_l[ni], 0, 0, 0);
#pragma unroll
                for (int di = 0; di < 4; di++)
                    acc_o[ni][di] = __builtin_amdgcn_mfma_f32_16x16x32_bf16(pa[ni], vb[di], acc_o[ni][di], 0, 0, 0);
            }
        }
        __syncthreads();
    }

    // normalize + store (coalesced along d = di*16 + l16)
#pragma unroll
    for (int ni = 0; ni < 2; ni++) {
#pragma unroll
        for (int r = 0; r < 4; r++) {
            float inv = __builtin_amdgcn_rcpf(acc_l[ni][r]);
            int row = w * 32 + ni * 16 + quad * 4 + r;
#pragma unroll
            for (int di = 0; di < 4; di++)
                Op[(size_t)row * 1024 + di * 16 + l16] = cvt1(acc_o[ni][di][r] * inv);
        }
    }
}

extern "C" void kernel_launch(void* const* d_in, const int* in_sizes, int n_in,
                              void* d_out, int out_size, void* d_ws, size_t ws_size,
                              hipStream_t stream)
{
    (void)in_sizes; (void)n_in; (void)out_size; (void)ws_size;
    // inputs (fp32): 0:x 4:Wq 5:bq 6:Wk 7:bk 8:Wv 9:bv 10:Wo 11:bo
    // 1,2,3,12..19: conditioning — mathematically cancels in softmax.
    const float* xf  = (const float*)d_in[0];
    const float* Wqf = (const float*)d_in[4];  const float* bqf = (const float*)d_in[5];
    const float* Wkf = (const float*)d_in[6];  const float* bkf = (const float*)d_in[7];
    const float* Wvf = (const float*)d_in[8];  const float* bvf = (const float*)d_in[9];
    const float* Wof = (const float*)d_in[10]; const float* bof = (const float*)d_in[11];

    u16* ws  = (u16*)d_ws;
    u16* Qw  = ws;                              // 8M el bf16 (pre-scaled by log2e/8)
    u16* Kw  = ws + (size_t)8388608;            // 8M el bf16
    u16* Vtw = ws + (size_t)16777216;           // 8M el bf16 [b*16+h][64][1024]
    u16* WT  = ws + (size_t)25165824;           // 4M el bf16 [4][n=1024][k=1024]
    u16* xb  = ws + (size_t)29360128;           // 8M el bf16 x; reused as AO after k_qkv
    u16* AO  = xb;

    k_prep<<<9216, 256, 0, stream>>>(xf, xb, Wqf, Wkf, Wvf, Wof, WT);
    k_qkv<<<dim3(24, 64), 256, 0, stream>>>(xb, WT, bqf, bkf, bvf, Qw, Vtw);
    k_attn<<<dim3(8, 128), 256, 0, stream>>>(Qw, Kw, Vtw, AO);
    k_out<<<dim3(8, 64), 256, 0, stream>>>(AO, WT + (size_t)3145728, bof, (float*)d_out);
}

// Round 8
// 266.411 us; speedup vs baseline: 1.1212x; 1.0147x over previous
//
#include <hip/hip_runtime.h>

typedef unsigned short u16;
typedef __attribute__((ext_vector_type(4))) unsigned short u16x4;
typedef __attribute__((ext_vector_type(2))) unsigned u32x2;
typedef __attribute__((ext_vector_type(8))) __bf16 bf16x8;
typedef __attribute__((ext_vector_type(2))) __bf16 bf16x2;
typedef __attribute__((ext_vector_type(4))) float f32x4;

#define DEV __device__ __forceinline__

DEV u16 f2b(float f) {
    union { float f; unsigned u; } v; v.f = f;
    unsigned r = v.u + 0x7FFFu + ((v.u >> 16) & 1u);
    return (u16)(r >> 16);
}
DEV unsigned pk2(float a, float b) {   // two f32 -> packed bf16x2 (RNE, hw cvt)
    bf16x2 t; t.x = (__bf16)a; t.y = (__bf16)b;
    union { bf16x2 v; unsigned u; } c; c.v = t; return c.u;
}
DEV u16 cvt1(float f) {
    __bf16 h = (__bf16)f;
    union { __bf16 h; u16 u; } c; c.h = h; return c.u;
}

// async global->LDS, 16B per lane; lds dest = wave-uniform base + lane*16
DEV void gl_lds16(const u16* g, const u16* l) {
    __builtin_amdgcn_global_load_lds(
        (__attribute__((address_space(1))) void*)(unsigned long long)g,
        (__attribute__((address_space(3))) void*)(unsigned long long)l,
        16, 0, 0);
}

// fused prep: blocks [0,8192) convert x fp32->bf16; [8192,9216) transpose W0..3
__global__ __launch_bounds__(256) void k_prep(const float* __restrict__ xf, u16* __restrict__ xb,
                                              const float* w0, const float* w1,
                                              const float* w2, const float* w3,
                                              u16* __restrict__ dst)
{
    __shared__ u16 t[64][68];
    int bx = blockIdx.x;
    if (bx < 8192) {
        size_t base = (size_t)bx * 1024 + threadIdx.x * 4;
        float4 v = *(const float4*)&xf[base];
        u16x4 o; o.x = f2b(v.x); o.y = f2b(v.y); o.z = f2b(v.z); o.w = f2b(v.w);
        *(u16x4*)&xb[base] = o;
        return;
    }
    bx -= 8192;
    int z = bx >> 8, tile = bx & 255;
    const float* src = z == 0 ? w0 : z == 1 ? w1 : z == 2 ? w2 : w3;
    u16* d = dst + (size_t)z * 1048576;
    int tx = threadIdx.x & 15, ty = threadIdx.x >> 4;
    int c0 = (tile & 15) * 64, r0 = (tile >> 4) * 64;
#pragma unroll
    for (int i = 0; i < 4; i++) {
        int r = ty + i * 16;
        float4 v = *(const float4*)&src[(size_t)(r0 + r) * 1024 + c0 + tx * 4];
        t[r][tx * 4 + 0] = f2b(v.x); t[r][tx * 4 + 1] = f2b(v.y);
        t[r][tx * 4 + 2] = f2b(v.z); t[r][tx * 4 + 3] = f2b(v.w);
    }
    __syncthreads();
#pragma unroll
    for (int i = 0; i < 4; i++) {
        int cl = ty + i * 16;
        u16x4 v;
        v.x = t[tx * 4 + 0][cl];
        v.y = t[tx * 4 + 1][cl];
        v.z = t[tx * 4 + 2][cl];
        v.w = t[tx * 4 + 3][cl];
        *(u16x4*)&d[(size_t)(c0 + cl) * 1024 + r0 + tx * 4] = v;
    }
}

// ---------------------------------------------------------------------------
// MI*32 x 128-tile bf16 GEMM (proven v3 structure): dbuf LDS (1 barrier/step),
// pair-row XOR swizzle (0 bank conflicts), row-dense coalesced epilogue.
// MI=4: 128-row tile (k_qkv, identical to round-7 proven path); MI=2: 64-row
// tile (k_out, doubles resident blocks). mode 0 bf16 / 1 Vt-scatter / 2 fp32.
// NOTE: no operand-swapped epilogue — token-on-lane-dim scatters stores and
// ~doubles HBM WRITE_SIZE (round-6 regression).
// ---------------------------------------------------------------------------
template <int MI, int MODE>
DEV void gemm_t(const u16* __restrict__ A, const u16* __restrict__ BT,
                const float* __restrict__ bias,
                u16* __restrict__ Cb, float* __restrict__ Cf,
                int N, int K, int m0, int n0, float oscale,
                u16* As, u16* Bs)
{
    const int tid = threadIdx.x;
    const int w = tid >> 6, lane = tid & 63, quad = lane >> 4, l16 = lane & 15;
    const int wr = w >> 1, wc = w & 1;
    const int ABUF = MI * 1024;
    f32x4 acc[MI][4] = {};
    const int NS = K >> 5;

    int soffB[2], ldstB[2];
#pragma unroll
    for (int i = 0; i < 2; i++) {
        int L = (w * 2 + i) * 512 + lane * 8;
        int pr = L >> 6, cp = (L >> 3) & 7;
        int c = cp ^ (pr & 7);
        soffB[i] = (pr * 2 + (c >> 2)) * K + (c & 3) * 8;
        ldstB[i] = (w * 2 + i) * 512;
    }
    int soffA[MI / 2], ldstA[MI / 2];
#pragma unroll
    for (int i = 0; i < MI / 2; i++) {
        int L = (w * (MI / 2) + i) * 512 + lane * 8;
        int pr = L >> 6, cp = (L >> 3) & 7;
        int c = cp ^ (pr & 7);
        soffA[i] = (pr * 2 + (c >> 2)) * K + (c & 3) * 8;
        ldstA[i] = (w * (MI / 2) + i) * 512;
    }
    const u16* Ap = A + (size_t)m0 * K;
    const u16* Bp = BT + (size_t)n0 * K;

    int aoff[MI], boff[4];
#pragma unroll
    for (int mi = 0; mi < MI; mi++) {
        int row = wr * (MI * 16) + mi * 16 + l16;
        aoff[mi] = (row >> 1) * 64 + (((((row & 1) << 2) | quad) ^ ((row >> 1) & 7)) << 3);
    }
#pragma unroll
    for (int ni = 0; ni < 4; ni++) {
        int rowb = wc * 64 + ni * 16 + l16;
        boff[ni] = (rowb >> 1) * 64 + (((((rowb & 1) << 2) | quad) ^ ((rowb >> 1) & 7)) << 3);
    }

#pragma unroll
    for (int i = 0; i < MI / 2; i++) gl_lds16(Ap + soffA[i], As + ldstA[i]);
#pragma unroll
    for (int i = 0; i < 2; i++) gl_lds16(Bp + soffB[i], Bs + ldstB[i]);
    __syncthreads();

    for (int s = 0; s < NS; s++) {
        const u16* curA = As + (s & 1) * ABUF;
        const u16* curB = Bs + (s & 1) * 4096;
        if (s + 1 < NS) {
            int kk = (s + 1) * 32;
            u16* nA = As + ((s + 1) & 1) * ABUF;
            u16* nB = Bs + ((s + 1) & 1) * 4096;
#pragma unroll
            for (int i = 0; i < MI / 2; i++) gl_lds16(Ap + soffA[i] + kk, nA + ldstA[i]);
#pragma unroll
            for (int i = 0; i < 2; i++) gl_lds16(Bp + soffB[i] + kk, nB + ldstB[i]);
        }
        bf16x8 a[MI], b[4];
#pragma unroll
        for (int mi = 0; mi < MI; mi++) a[mi] = *(const bf16x8*)&curA[aoff[mi]];
#pragma unroll
        for (int ni = 0; ni < 4; ni++) b[ni] = *(const bf16x8*)&curB[boff[ni]];
#pragma unroll
        for (int mi = 0; mi < MI; mi++)
#pragma unroll
            for (int ni = 0; ni < 4; ni++)
                acc[mi][ni] = __builtin_amdgcn_mfma_f32_16x16x32_bf16(a[mi], b[ni], acc[mi][ni], 0, 0, 0);
        __syncthreads();
    }

    float bs[4];
#pragma unroll
    for (int ni = 0; ni < 4; ni++)
        bs[ni] = bias[n0 + wc * 64 + ni * 16 + l16];

    if (MODE == 0) {
#pragma unroll
        for (int mi = 0; mi < MI; mi++) {
            int row = m0 + wr * (MI * 16) + mi * 16 + quad * 4;
#pragma unroll
            for (int ni = 0; ni < 4; ni++) {
                int col = n0 + wc * 64 + ni * 16 + l16;
#pragma unroll
                for (int r2 = 0; r2 < 4; r2++)
                    Cb[(size_t)(row + r2) * N + col] = f2b((acc[mi][ni][r2] + bs[ni]) * oscale);
            }
        }
    } else if (MODE == 1) {
        int bb = m0 >> 10;
        int nbase = (m0 & 1023) + wr * (MI * 16);
#pragma unroll
        for (int mi = 0; mi < MI; mi++) {
            int nrow = nbase + mi * 16 + quad * 4;
#pragma unroll
            for (int ni = 0; ni < 4; ni++) {
                int col = n0 + wc * 64 + ni * 16 + l16;
                int hh = col >> 6, dd = col & 63;
                u16x4 pk;
                pk.x = f2b(acc[mi][ni][0] + bs[ni]);
                pk.y = f2b(acc[mi][ni][1] + bs[ni]);
                pk.z = f2b(acc[mi][ni][2] + bs[ni]);
                pk.w = f2b(acc[mi][ni][3] + bs[ni]);
                *(u16x4*)&Cb[(size_t)(bb * 16 + hh) * 65536 + (size_t)dd * 1024 + nrow] = pk;
            }
        }
    } else {
#pragma unroll
        for (int mi = 0; mi < MI; mi++) {
            int row = m0 + wr * (MI * 16) + mi * 16 + quad * 4;
#pragma unroll
            for (int ni = 0; ni < 4; ni++) {
                int col = n0 + wc * 64 + ni * 16 + l16;
#pragma unroll
                for (int r2 = 0; r2 < 4; r2++)
                    Cf[(size_t)(row + r2) * N + col] = acc[mi][ni][r2] + bs[ni];
            }
        }
    }
}

// fused Q/K/V projection: grid (24, 64); Q pre-scaled by log2(e)/8
__global__ __launch_bounds__(256, 4) void k_qkv(const u16* __restrict__ x, const u16* __restrict__ WT,
                                                const float* __restrict__ bq, const float* __restrict__ bk,
                                                const float* __restrict__ bv,
                                                u16* __restrict__ QK, u16* __restrict__ Vt)
{
    __shared__ u16 As[8192], Bs[8192];
    int sel = blockIdx.x >> 3;
    int m0 = blockIdx.y * 128, n0 = (blockIdx.x & 7) * 128;
    if (sel == 2) {
        gemm_t<4, 1>(x, WT + (size_t)2 * 1048576, bv, Vt, (float*)0, 1024, 1024, m0, n0, 1.0f, As, Bs);
    } else if (sel == 0) {
        gemm_t<4, 0>(x, WT, bq, QK, (float*)0, 1024, 1024, m0, n0, 0.18033688011f, As, Bs);
    } else {
        gemm_t<4, 0>(x, WT + (size_t)1048576, bk, QK + (size_t)8388608, (float*)0,
                     1024, 1024, m0, n0, 1.0f, As, Bs);
    }
}

// output projection (fp32 out), 64-row tiles for 4 blocks/CU: grid (8, 128)
__global__ __launch_bounds__(256, 4) void k_out(const u16* __restrict__ A, const u16* __restrict__ WoT,
                                                const float* __restrict__ bo, float* __restrict__ C)
{
    __shared__ u16 As[4096], Bs[8192];
    gemm_t<2, 2>(A, WoT, bo, (u16*)0, C, 1024, 1024, blockIdx.y * 64, blockIdx.x * 128, 1.0f, As, Bs);
}

// ---------------------------------------------------------------------------
// attention v5: 32-key K/V tiles -> 26 KB LDS -> 4 blocks/CU all-resident
// (was 51 KB / 3 blocks + tail). Wave-private q rows, dbuf K/V, 1 barrier/kt,
// XOR-swizzled staging, ones-MFMA row-sum, coalesced O store. grid (8, 128)
// LDS: [0,8192) KV dbuf = 2 x (K[32][64] 2048 | V[64][32] 2048); Q staged
// here pre-loop; [8192,13312) Ps: 4 waves x 32 q x 40 u16 (stride 40 keeps
// 16B alignment and bank-uniform access).
// ---------------------------------------------------------------------------
__global__ __launch_bounds__(256, 4) void k_attn(const u16* __restrict__ Q, const u16* __restrict__ K,
                                                 const u16* __restrict__ Vt, u16* __restrict__ O)
{
    __shared__ u16 lds[13312];
    const int tid = threadIdx.x, w = tid >> 6, lane = tid & 63, quad = lane >> 4, l16 = lane & 15;
    const int bh = blockIdx.y, b = bh >> 4, h = bh & 15;
    const int q0 = blockIdx.x * 128;
    const u16* Qp = Q + ((size_t)b * 1024 + q0) * 1024 + h * 64;
    const u16* Kp = K + (size_t)b * 1048576 + h * 64;
    const u16* Vp = Vt + (size_t)bh * 65536;
    u16* Op = O + ((size_t)b * 1024 + q0) * 1024 + h * 64;
    u16* Pw = lds + 8192 + w * 1280;   // 32 rows x 40 u16, wave-private

    // stage Q [128][64] swizzled into [0,8192)
#pragma unroll
    for (int i = 0; i < 4; i++) {
        int g = (w * 4 + i) * 64 + lane;
        int row = g >> 3, c = (g & 7) ^ (row & 7);
        gl_lds16(Qp + (size_t)row * 1024 + c * 8, lds + (w * 4 + i) * 512);
    }
    __syncthreads();
    bf16x8 qa[2][2];
#pragma unroll
    for (int ni = 0; ni < 2; ni++)
#pragma unroll
        for (int d2 = 0; d2 < 2; d2++)
            qa[ni][d2] = *(const bf16x8*)&lds[(w * 32 + ni * 16 + l16) * 64 + ((d2 * 4 + quad) ^ (l16 & 7)) * 8];
    __syncthreads();   // all waves done reading Q before KV staging overwrites it

    // stage kt0 into buf0
    {
        int g = w * 64 + lane;
        int row = g >> 3, c = (g & 7) ^ (row & 7);
        gl_lds16(Kp + (size_t)row * 1024 + c * 8, lds + w * 512);
        int rv = g >> 2, cv = (g & 3) ^ (rv & 3);
        gl_lds16(Vp + (size_t)rv * 1024 + cv * 8, lds + 2048 + w * 512);
    }
    __syncthreads();

    bf16x8 ones;
#pragma unroll
    for (int j = 0; j < 8; j++) ones[j] = (__bf16)1.0f;

    f32x4 acc_o[2][4] = {};   // [ni][di]: D[q][d], col=d(l16), row=q-part
    f32x4 acc_l[2] = {};      // [ni]: l(q), row-aligned with acc_o

    for (int kt = 0; kt < 32; kt++) {
        const u16* buf = lds + (kt & 1) * 4096;
        if (kt < 31) {
            int k0n = (kt + 1) * 32;
            u16* dst = lds + ((kt + 1) & 1) * 4096;
            int g = w * 64 + lane;
            int row = g >> 3, c = (g & 7) ^ (row & 7);
            gl_lds16(Kp + (size_t)(k0n + row) * 1024 + c * 8, dst + w * 512);
            int rv = g >> 2, cv = (g & 3) ^ (rv & 3);
            gl_lds16(Vp + (size_t)rv * 1024 + k0n + cv * 8, dst + 2048 + w * 512);
        }

        // S^T: D[k=mi*16+quad*4+reg][q=w*32+ni*16+l16], accumulate over d halves
        f32x4 s[2][2] = {};
#pragma unroll
        for (int d2 = 0; d2 < 2; d2++) {
            bf16x8 ka[2];
#pragma unroll
            for (int mi = 0; mi < 2; mi++)
                ka[mi] = *(const bf16x8*)&buf[(mi * 16 + l16) * 64 + ((d2 * 4 + quad) ^ (l16 & 7)) * 8];
#pragma unroll
            for (int mi = 0; mi < 2; mi++)
#pragma unroll
                for (int ni = 0; ni < 2; ni++)
                    s[mi][ni] = __builtin_amdgcn_mfma_f32_16x16x32_bf16(ka[mi], qa[ni][d2], s[mi][ni], 0, 0, 0);
        }

        // exp2 (Q pre-scaled), pack 4 consecutive k -> wave-private Ps
#pragma unroll
        for (int ni = 0; ni < 2; ni++)
#pragma unroll
            for (int mi = 0; mi < 2; mi++) {
                float e0 = __builtin_amdgcn_exp2f(s[mi][ni][0]);
                float e1 = __builtin_amdgcn_exp2f(s[mi][ni][1]);
                float e2 = __builtin_amdgcn_exp2f(s[mi][ni][2]);
                float e3 = __builtin_amdgcn_exp2f(s[mi][ni][3]);
                u32x2 pk; pk.x = pk2(e0, e1); pk.y = pk2(e2, e3);
                *(u32x2*)&Pw[(ni * 16 + l16) * 40 + mi * 16 + quad * 4] = pk;
            }

        // O[q][d] += P[q][k32] V[k32][d]; l(q) += P*ones; same-wave LDS RAW
        {
            bf16x8 pa[2], vb[4];
#pragma unroll
            for (int ni = 0; ni < 2; ni++)
                pa[ni] = *(const bf16x8*)&Pw[(ni * 16 + l16) * 40 + quad * 8];
#pragma unroll
            for (int di = 0; di < 4; di++)
                vb[di] = *(const bf16x8*)&buf[2048 + (di * 16 + l16) * 32 + (quad ^ (l16 & 3)) * 8];
#pragma unroll
            for (int ni = 0; ni < 2; ni++) {
                acc_l[ni] = __builtin_amdgcn_mfma_f32_16x16x32_bf16(pa[ni], ones, acc_l[ni], 0, 0, 0);
#pragma unroll
                for (int di = 0; di < 4; di++)
                    acc_o[ni][di] = __builtin_amdgcn_mfma_f32_16x16x32_bf16(pa[ni], vb[di], acc_o[ni][di], 0, 0, 0);
            }
        }
        __syncthreads();
    }

    // normalize + store (coalesced along d = di*16 + l16)
#pragma unroll
    for (int ni = 0; ni < 2; ni++) {
#pragma unroll
        for (int r = 0; r < 4; r++) {
            float inv = __builtin_amdgcn_rcpf(acc_l[ni][r]);
            int row = w * 32 + ni * 16 + quad * 4 + r;
#pragma unroll
            for (int di = 0; di < 4; di++)
                Op[(size_t)row * 1024 + di * 16 + l16] = cvt1(acc_o[ni][di][r] * inv);
        }
    }
}

extern "C" void kernel_launch(void* const* d_in, const int* in_sizes, int n_in,
                              void* d_out, int out_size, void* d_ws, size_t ws_size,
                              hipStream_t stream)
{
    (void)in_sizes; (void)n_in; (void)out_size; (void)ws_size;
    // inputs (fp32): 0:x 4:Wq 5:bq 6:Wk 7:bk 8:Wv 9:bv 10:Wo 11:bo
    // 1,2,3,12..19: conditioning — mathematically cancels in softmax.
    const float* xf  = (const float*)d_in[0];
    const float* Wqf = (const float*)d_in[4];  const float* bqf = (const float*)d_in[5];
    const float* Wkf = (const float*)d_in[6];  const float* bkf = (const float*)d_in[7];
    const float* Wvf = (const float*)d_in[8];  const float* bvf = (const float*)d_in[9];
    const float* Wof = (const float*)d_in[10]; const float* bof = (const float*)d_in[11];

    u16* ws  = (u16*)d_ws;
    u16* Qw  = ws;                              // 8M el bf16 (pre-scaled by log2e/8)
    u16* Kw  = ws + (size_t)8388608;            // 8M el bf16
    u16* Vtw = ws + (size_t)16777216;           // 8M el bf16 [b*16+h][64][1024]
    u16* WT  = ws + (size_t)25165824;           // 4M el bf16 [4][n=1024][k=1024]
    u16* xb  = ws + (size_t)29360128;           // 8M el bf16 x; reused as AO after k_qkv
    u16* AO  = xb;

    k_prep<<<9216, 256, 0, stream>>>(xf, xb, Wqf, Wkf, Wvf, Wof, WT);
    k_qkv<<<dim3(24, 64), 256, 0, stream>>>(xb, WT, bqf, bkf, bvf, Qw, Vtw);
    k_attn<<<dim3(8, 128), 256, 0, stream>>>(Qw, Kw, Vtw, AO);
    k_out<<<dim3(8, 128), 256, 0, stream>>>(AO, WT + (size_t)3145728, bof, (float*)d_out);
}